// Round 25
// baseline (72.101 us; speedup 1.0000x reference)
//
#include <hip/hip_runtime.h>
#include <math.h>

#define PR 30            // padded rows
#define PC 32            // padded col stride

__device__ __forceinline__ void tap3(const float4 a, const float2 b,
                                     const float w0, const float w1, const float w2,
                                     float4& acc) {
    acc.x += fabsf(a.x - w0) + fabsf(a.y - w1) + fabsf(a.z - w2);
    acc.y += fabsf(a.y - w0) + fabsf(a.z - w1) + fabsf(a.w - w2);
    acc.z += fabsf(a.z - w0) + fabsf(a.w - w1) + fabsf(b.x - w2);
    acc.w += fabsf(a.w - w0) + fabsf(b.x - w1) + fabsf(b.y - w2);
}

// ---------------- K1: 1x1 adder 256->64 -> PADDED h1p (halos folded). R22 proven. ----------------
__global__ __launch_bounds__(448) void k1_adder1x1(const float* __restrict__ x,
                                                   const float* __restrict__ w1,
                                                   float* __restrict__ h1p) {
    __shared__ __align__(16) float smem[7168];   // ws [256][20] (5120) union pl (7168)
    float*  ws  = smem;
    float4* pl4 = (float4*)smem;
    const int tid    = threadIdx.x;
    const int cog    = tid & 3;
    const int pxg    = (tid >> 2) % 7;
    const int cic    = tid / 28;                 // 0..15
    const int n      = blockIdx.x / 28;
    const int y      = blockIdx.x % 28;
    const int px0    = y * 28 + pxg * 4;
    const int cobase = blockIdx.y * 16;

    for (int idx = tid; idx < 4096; idx += 448) {
        int co = idx >> 8, ci = idx & 255;
        ws[ci * 20 + co] = w1[(size_t)(cobase + co) * 256 + ci];
    }
    __syncthreads();

    float4 acc0 = {0,0,0,0}, acc1 = acc0, acc2 = acc0, acc3 = acc0;
    const float* xp = x + ((size_t)n * 256 + cic * 16) * 784 + px0;
    const float* wp = ws + (cic * 16) * 20 + cog * 4;
    #pragma unroll 8
    for (int i = 0; i < 16; ++i) {
        float4 u = *(const float4*)(xp + (size_t)i * 784);
        float4 w = *(const float4*)(wp + i * 20);
        acc0.x += fabsf(u.x - w.x); acc0.y += fabsf(u.y - w.x); acc0.z += fabsf(u.z - w.x); acc0.w += fabsf(u.w - w.x);
        acc1.x += fabsf(u.x - w.y); acc1.y += fabsf(u.y - w.y); acc1.z += fabsf(u.z - w.y); acc1.w += fabsf(u.w - w.y);
        acc2.x += fabsf(u.x - w.z); acc2.y += fabsf(u.y - w.z); acc2.z += fabsf(u.z - w.z); acc2.w += fabsf(u.w - w.z);
        acc3.x += fabsf(u.x - w.w); acc3.y += fabsf(u.y - w.w); acc3.z += fabsf(u.z - w.w); acc3.w += fabsf(u.w - w.w);
    }
    __syncthreads();
    const int pbase = pxg * 16 + cog * 4;
    pl4[cic * 112 + pbase + 0] = acc0;
    pl4[cic * 112 + pbase + 1] = acc1;
    pl4[cic * 112 + pbase + 2] = acc2;
    pl4[cic * 112 + pbase + 3] = acc3;
    __syncthreads();

    if (tid < 112) {
        const int rpxg = tid >> 4;
        const int rcog = (tid >> 2) & 3;
        const int j    = tid & 3;
        const int rb   = rpxg * 16 + rcog * 4 + j;
        float4 s = pl4[rb];
        #pragma unroll
        for (int c = 1; c < 16; ++c) {
            float4 t = pl4[c * 112 + rb];
            s.x += t.x; s.y += t.y; s.z += t.z; s.w += t.w;
        }
        const int co = cobase + rcog * 4 + j;
        float* op = h1p + ((size_t)(n * 64 + co) * PR + y + 1) * PC + rpxg * 4 + 1;
        op[0] = -s.x; op[1] = -s.y; op[2] = -s.z; op[3] = -s.w;
        if (rpxg == 0) op[-1] = 0.f;
        if (rpxg == 6) { op[4] = 0.f; op[5] = 0.f; op[6] = 0.f; }
    }
    if (y == 0 || y == 27) {
        const int prow = (y == 0) ? 0 : 29;
        for (int idx = tid; idx < 512; idx += 448) {
            int coi = idx >> 5, col = idx & 31;
            h1p[((size_t)(n * 64 + cobase + coi) * PR + prow) * PC + col] = 0.f;
        }
    }
}

// ---------------- K2: PEG depthwise + BN1 + ReLU + h2p halos + w2t/w3t transposes. R22 proven. ----------------
__global__ __launch_bounds__(256) void k2_peg_bn_relu(const float* __restrict__ h1p,
                                                      const float* __restrict__ wp,
                                                      const float* __restrict__ w2,
                                                      const float* __restrict__ w3,
                                                      const float* __restrict__ g1,
                                                      const float* __restrict__ b1,
                                                      const float* __restrict__ m1,
                                                      const float* __restrict__ v1,
                                                      float* __restrict__ h2p,
                                                      float* __restrict__ w2t,
                                                      float* __restrict__ w3t) {
    const int t = blockIdx.x * 256 + threadIdx.x;
    if (t < 100352) {
        const int pxq = t % 196;
        const int c   = (t / 196) & 63;
        const int n   = t / (196 * 64);
        const int p0  = pxq * 4;
        const int y   = p0 / 28, xx = p0 % 28;
        const float* base = h1p + ((size_t)(n * 64 + c) * PR + y) * PC + xx;
        const float* wc   = wp + c * 9;
        float4 acc = {0,0,0,0};
        #pragma unroll
        for (int kh = 0; kh < 3; ++kh) {
            float4 a = *(const float4*)(base + kh * PC);
            float2 b = *(const float2*)(base + kh * PC + 4);
            tap3(a, b, wc[kh * 3 + 0], wc[kh * 3 + 1], wc[kh * 3 + 2], acc);
        }
        float inv = g1[c] * rsqrtf(v1[c] + 1e-5f);
        float bb  = b1[c] - m1[c] * inv;
        float* op = h2p + ((size_t)(n * 64 + c) * PR + y + 1) * PC + xx + 1;
        op[0] = fmaxf(-acc.x * inv + bb, 0.f);
        op[1] = fmaxf(-acc.y * inv + bb, 0.f);
        op[2] = fmaxf(-acc.z * inv + bb, 0.f);
        op[3] = fmaxf(-acc.w * inv + bb, 0.f);
    } else if (t < 190464) {
        int i = t - 100352;
        int plane = i / 176, r = i % 176;
        int row, col;
        if (r < 64) { row = (r >> 5) * 29; col = r & 31; }
        else { int j = r - 64; row = 1 + (j >> 2); int k = j & 3; col = k ? 28 + k : 0; }
        h2p[(size_t)plane * (PR * PC) + row * PC + col] = 0.f;
    } else if (t < 227328) {
        int i = t - 190464;
        int r = i >> 6, c2 = i & 63;
        w2t[i] = w2[(size_t)c2 * 576 + r];
    } else if (t < 243712) {
        int i = t - 227328;
        int ci = i >> 8, c2 = i & 255;
        w3t[i] = w3[(size_t)c2 * 64 + ci];
    }
}

// ---------------- K3: 3x3 adder partials (8-ci slice) -> h3part. R22 proven. ----------------
// grid (7 Yq, 8 ciQ, 8 n) = 448 blocks, block 512 = 8 waves (wave = co-oct).
__global__ __launch_bounds__(512) void k3_part(const float* __restrict__ h2p,
                                               const float* __restrict__ w2t,
                                               float* __restrict__ h3part) {
    __shared__ __align__(16) float h2t[1728];    // [8 ci][6 rows][36]
    __shared__ __align__(16) float wt[4896];     // [72 r = ci*9+tap][68]
    const int tid  = threadIdx.x;
    const int lane = tid & 63;
    const int oct  = __builtin_amdgcn_readfirstlane(tid >> 6);   // 0..7
    const int col  = lane & 31;
    const int cih  = lane >> 5;          // 0..1
    const int Y0   = blockIdx.x * 4;     // output rows Y0..Y0+3
    const int ciQ  = blockIdx.y;         // 8 ci per block
    const int n    = blockIdx.z;

    for (int i = tid; i < 384; i += 512) {       // h2t: 8 ci x 6 rows x 8 f4
        int ci = i / 48, rem = i % 48;
        int r = rem >> 3, c4 = rem & 7;
        *(float4*)(h2t + ci * 216 + r * 36 + c4 * 4) =
            *(const float4*)(h2p + ((size_t)(n * 64 + ciQ * 8 + ci) * PR + Y0 + r) * PC + c4 * 4);
    }
    for (int i = tid; i < 1152; i += 512) {      // wt: 72 rows x 16 f4
        int row = i >> 4, c4 = i & 15;
        *(float4*)(wt + row * 68 + c4 * 4) =
            *(const float4*)(w2t + ((size_t)ciQ * 72 + row) * 64 + c4 * 4);
    }
    __syncthreads();

    float acc[4][8];
    #pragma unroll
    for (int r = 0; r < 4; ++r)
        #pragma unroll
        for (int j = 0; j < 8; ++j) acc[r][j] = 0.f;

    #pragma unroll
    for (int i = 0; i < 4; ++i) {
        const int ci_l = cih * 4 + i;            // 0..7
        float win[6][3];
        #pragma unroll
        for (int r = 0; r < 6; ++r)
            #pragma unroll
            for (int kw = 0; kw < 3; ++kw)
                win[r][kw] = h2t[ci_l * 216 + r * 36 + col + kw];
        const float* wrow = wt + ci_l * 612 + oct * 8;
        #pragma unroll
        for (int kh = 0; kh < 3; ++kh) {
            #pragma unroll
            for (int kw = 0; kw < 3; ++kw) {
                float4 wa = *(const float4*)(wrow + (kh * 3 + kw) * 68);
                float4 wb = *(const float4*)(wrow + (kh * 3 + kw) * 68 + 4);
                #pragma unroll
                for (int r = 0; r < 4; ++r) {
                    const float xv = win[r + kh][kw];
                    acc[r][0] += fabsf(xv - wa.x); acc[r][1] += fabsf(xv - wa.y);
                    acc[r][2] += fabsf(xv - wa.z); acc[r][3] += fabsf(xv - wa.w);
                    acc[r][4] += fabsf(xv - wb.x); acc[r][5] += fabsf(xv - wb.y);
                    acc[r][6] += fabsf(xv - wb.z); acc[r][7] += fabsf(xv - wb.w);
                }
            }
        }
    }
    #pragma unroll
    for (int r = 0; r < 4; ++r)
        #pragma unroll
        for (int j = 0; j < 8; ++j)
            acc[r][j] += __shfl_xor(acc[r][j], 32, 64);

    if (cih == 0 && col < 28) {
        #pragma unroll
        for (int r = 0; r < 4; ++r)
            #pragma unroll
            for (int j = 0; j < 8; ++j)
                h3part[(((size_t)ciQ * 8 + n) * 64 + oct * 8 + j) * 784 + (Y0 + r) * 28 + col] = acc[r][j];
    }
}

// ---------------- K6: sum 8 partials + BN2 + ReLU + 1x1 adder 64->256 + BN3 + res + ReLU ----------------
// grid (28 Y, 8 n) = 224 blocks, block 512. SINGLE CHANGE vs R24: w3 read directly
// from global w3t in phase B (per-lane distinct, coalesced 1KB/wave-instr); w3s LDS
// buffer + staging deleted -> LDS 75.6 KB -> 8 KB, LDS pipe load halved.
__global__ __launch_bounds__(512) void k6_fused(const float* __restrict__ h3part,
                                                const float* __restrict__ w3t,
                                                const float* __restrict__ x,
                                                const float* __restrict__ g2,
                                                const float* __restrict__ b2,
                                                const float* __restrict__ m2,
                                                const float* __restrict__ v2,
                                                const float* __restrict__ g3,
                                                const float* __restrict__ b3,
                                                const float* __restrict__ m3,
                                                const float* __restrict__ v3,
                                                float* __restrict__ out) {
    __shared__ __align__(16) float h3t[2048];    // [64 ci][32]
    const int tid = threadIdx.x;
    const int Y   = blockIdx.x;
    const int n   = blockIdx.y;

    if (tid < 448) {
        const int co = tid / 7, c4 = tid % 7;
        size_t base = ((size_t)n * 64 + co) * 784 + Y * 28 + c4 * 4;
        const size_t qstride = (size_t)8 * 64 * 784;
        float4 s = *(const float4*)(h3part + base);
        #pragma unroll
        for (int qq = 1; qq < 8; ++qq) {
            float4 t = *(const float4*)(h3part + qq * qstride + base);
            s.x += t.x; s.y += t.y; s.z += t.z; s.w += t.w;
        }
        float inv = g2[co] * rsqrtf(v2[co] + 1e-5f);
        float bb  = b2[co] - m2[co] * inv;
        float4 o;
        o.x = fmaxf(-s.x * inv + bb, 0.f);
        o.y = fmaxf(-s.y * inv + bb, 0.f);
        o.z = fmaxf(-s.z * inv + bb, 0.f);
        o.w = fmaxf(-s.w * inv + bb, 0.f);
        *(float4*)(h3t + co * 32 + c4 * 4) = o;
    }
    __syncthreads();

    {
        const int bl = tid & 63;          // co-quad: co = bl*4..+3
        const int pg = tid >> 6;          // px-quad group; px = pg*4..+3
        float4 c0 = {0,0,0,0}, c1 = c0, c2 = c0, c3 = c0;
        const float* hb = h3t + pg * 4;
        const float* wb = w3t + bl * 4;
        #pragma unroll 8
        for (int ci = 0; ci < 64; ++ci) {
            float4 h = *(const float4*)(hb + ci * 32);           // LDS broadcast
            float4 w = *(const float4*)(wb + (size_t)ci * 256);  // global, coalesced
            c0.x += fabsf(h.x - w.x); c0.y += fabsf(h.y - w.x); c0.z += fabsf(h.z - w.x); c0.w += fabsf(h.w - w.x);
            c1.x += fabsf(h.x - w.y); c1.y += fabsf(h.y - w.y); c1.z += fabsf(h.z - w.y); c1.w += fabsf(h.w - w.y);
            c2.x += fabsf(h.x - w.z); c2.y += fabsf(h.y - w.z); c2.z += fabsf(h.z - w.z); c2.w += fabsf(h.w - w.z);
            c3.x += fabsf(h.x - w.w); c3.y += fabsf(h.y - w.w); c3.z += fabsf(h.z - w.w); c3.w += fabsf(h.w - w.w);
        }
        if (pg < 7) {
            float4 accs[4] = {c0, c1, c2, c3};
            #pragma unroll
            for (int j = 0; j < 4; ++j) {
                const int co = bl * 4 + j;
                float inv = g3[co] * rsqrtf(v3[co] + 1e-5f);
                float bb  = b3[co] - m3[co] * inv;
                size_t obase = ((size_t)n * 256 + co) * 784 + Y * 28 + pg * 4;
                float4 r = *(const float4*)(x + obase);
                float4 o;
                o.x = fmaxf(-accs[j].x * inv + bb + r.x, 0.f);
                o.y = fmaxf(-accs[j].y * inv + bb + r.y, 0.f);
                o.z = fmaxf(-accs[j].z * inv + bb + r.z, 0.f);
                o.w = fmaxf(-accs[j].w * inv + bb + r.w, 0.f);
                *(float4*)(out + obase) = o;
            }
        }
    }
}

extern "C" void kernel_launch(void* const* d_in, const int* in_sizes, int n_in,
                              void* d_out, int out_size, void* d_ws, size_t ws_size,
                              hipStream_t stream) {
    const float* x  = (const float*)d_in[0];
    const float* w1 = (const float*)d_in[1];
    const float* wp = (const float*)d_in[2];
    const float* w2 = (const float*)d_in[3];
    const float* w3 = (const float*)d_in[4];
    const float* g1 = (const float*)d_in[5];
    const float* b1 = (const float*)d_in[6];
    const float* m1 = (const float*)d_in[7];
    const float* v1 = (const float*)d_in[8];
    const float* g2 = (const float*)d_in[9];
    const float* b2 = (const float*)d_in[10];
    const float* m2 = (const float*)d_in[11];
    const float* v2 = (const float*)d_in[12];
    const float* g3 = (const float*)d_in[13];
    const float* b3 = (const float*)d_in[14];
    const float* m3 = (const float*)d_in[15];
    const float* v3 = (const float*)d_in[16];
    float* out = (float*)d_out;

    float* wsf     = (float*)d_ws;
    float* h1p     = wsf;                 // 491520
    float* h2p     = wsf + 491520;        // 491520
    float* w2t     = wsf + 983040;        // 36864 [576 r][64 co]
    float* w3t     = wsf + 1019904;       // 16384 [64 ci][256 co]
    float* h3part  = wsf + 1036288;       // 8*8*64*784 = 3211264

    k1_adder1x1<<<dim3(224, 4), 448, 0, stream>>>(x, w1, h1p);
    k2_peg_bn_relu<<<dim3(952), 256, 0, stream>>>(h1p, wp, w2, w3,
                                                  g1, b1, m1, v1, h2p, w2t, w3t);
    k3_part<<<dim3(7, 8, 8), 512, 0, stream>>>(h2p, w2t, h3part);
    k6_fused<<<dim3(28, 8), 512, 0, stream>>>(h3part, w3t, x,
                                              g2, b2, m2, v2, g3, b3, m3, v3, out);
}

// Round 26
// 60.052 us; speedup vs baseline: 1.2006x; 1.2006x over previous
//
#include <hip/hip_runtime.h>
#include <math.h>

#define PR 30            // padded rows
#define PC 32            // padded col stride

__device__ __forceinline__ void tap3(const float4 a, const float2 b,
                                     const float w0, const float w1, const float w2,
                                     float4& acc) {
    acc.x += fabsf(a.x - w0) + fabsf(a.y - w1) + fabsf(a.z - w2);
    acc.y += fabsf(a.y - w0) + fabsf(a.z - w1) + fabsf(a.w - w2);
    acc.z += fabsf(a.z - w0) + fabsf(a.w - w1) + fabsf(b.x - w2);
    acc.w += fabsf(a.w - w0) + fabsf(b.x - w1) + fabsf(b.y - w2);
}

// ---------------- K1: 1x1 adder 256->64 -> PADDED h1p (halos folded). R22 proven. ----------------
__global__ __launch_bounds__(448) void k1_adder1x1(const float* __restrict__ x,
                                                   const float* __restrict__ w1,
                                                   float* __restrict__ h1p) {
    __shared__ __align__(16) float smem[7168];   // ws [256][20] (5120) union pl (7168)
    float*  ws  = smem;
    float4* pl4 = (float4*)smem;
    const int tid    = threadIdx.x;
    const int cog    = tid & 3;
    const int pxg    = (tid >> 2) % 7;
    const int cic    = tid / 28;                 // 0..15
    const int n      = blockIdx.x / 28;
    const int y      = blockIdx.x % 28;
    const int px0    = y * 28 + pxg * 4;
    const int cobase = blockIdx.y * 16;

    for (int idx = tid; idx < 4096; idx += 448) {
        int co = idx >> 8, ci = idx & 255;
        ws[ci * 20 + co] = w1[(size_t)(cobase + co) * 256 + ci];
    }
    __syncthreads();

    float4 acc0 = {0,0,0,0}, acc1 = acc0, acc2 = acc0, acc3 = acc0;
    const float* xp = x + ((size_t)n * 256 + cic * 16) * 784 + px0;
    const float* wp = ws + (cic * 16) * 20 + cog * 4;
    #pragma unroll 8
    for (int i = 0; i < 16; ++i) {
        float4 u = *(const float4*)(xp + (size_t)i * 784);
        float4 w = *(const float4*)(wp + i * 20);
        acc0.x += fabsf(u.x - w.x); acc0.y += fabsf(u.y - w.x); acc0.z += fabsf(u.z - w.x); acc0.w += fabsf(u.w - w.x);
        acc1.x += fabsf(u.x - w.y); acc1.y += fabsf(u.y - w.y); acc1.z += fabsf(u.z - w.y); acc1.w += fabsf(u.w - w.y);
        acc2.x += fabsf(u.x - w.z); acc2.y += fabsf(u.y - w.z); acc2.z += fabsf(u.z - w.z); acc2.w += fabsf(u.w - w.z);
        acc3.x += fabsf(u.x - w.w); acc3.y += fabsf(u.y - w.w); acc3.z += fabsf(u.z - w.w); acc3.w += fabsf(u.w - w.w);
    }
    __syncthreads();
    const int pbase = pxg * 16 + cog * 4;
    pl4[cic * 112 + pbase + 0] = acc0;
    pl4[cic * 112 + pbase + 1] = acc1;
    pl4[cic * 112 + pbase + 2] = acc2;
    pl4[cic * 112 + pbase + 3] = acc3;
    __syncthreads();

    if (tid < 112) {
        const int rpxg = tid >> 4;
        const int rcog = (tid >> 2) & 3;
        const int j    = tid & 3;
        const int rb   = rpxg * 16 + rcog * 4 + j;
        float4 s = pl4[rb];
        #pragma unroll
        for (int c = 1; c < 16; ++c) {
            float4 t = pl4[c * 112 + rb];
            s.x += t.x; s.y += t.y; s.z += t.z; s.w += t.w;
        }
        const int co = cobase + rcog * 4 + j;
        float* op = h1p + ((size_t)(n * 64 + co) * PR + y + 1) * PC + rpxg * 4 + 1;
        op[0] = -s.x; op[1] = -s.y; op[2] = -s.z; op[3] = -s.w;
        if (rpxg == 0) op[-1] = 0.f;
        if (rpxg == 6) { op[4] = 0.f; op[5] = 0.f; op[6] = 0.f; }
    }
    if (y == 0 || y == 27) {
        const int prow = (y == 0) ? 0 : 29;
        for (int idx = tid; idx < 512; idx += 448) {
            int coi = idx >> 5, col = idx & 31;
            h1p[((size_t)(n * 64 + cobase + coi) * PR + prow) * PC + col] = 0.f;
        }
    }
}

// ---------------- K2: PEG depthwise + BN1 + ReLU + h2p halos + w2t/w3t transposes. R22 proven. ----------------
__global__ __launch_bounds__(256) void k2_peg_bn_relu(const float* __restrict__ h1p,
                                                      const float* __restrict__ wp,
                                                      const float* __restrict__ w2,
                                                      const float* __restrict__ w3,
                                                      const float* __restrict__ g1,
                                                      const float* __restrict__ b1,
                                                      const float* __restrict__ m1,
                                                      const float* __restrict__ v1,
                                                      float* __restrict__ h2p,
                                                      float* __restrict__ w2t,
                                                      float* __restrict__ w3t) {
    const int t = blockIdx.x * 256 + threadIdx.x;
    if (t < 100352) {
        const int pxq = t % 196;
        const int c   = (t / 196) & 63;
        const int n   = t / (196 * 64);
        const int p0  = pxq * 4;
        const int y   = p0 / 28, xx = p0 % 28;
        const float* base = h1p + ((size_t)(n * 64 + c) * PR + y) * PC + xx;
        const float* wc   = wp + c * 9;
        float4 acc = {0,0,0,0};
        #pragma unroll
        for (int kh = 0; kh < 3; ++kh) {
            float4 a = *(const float4*)(base + kh * PC);
            float2 b = *(const float2*)(base + kh * PC + 4);
            tap3(a, b, wc[kh * 3 + 0], wc[kh * 3 + 1], wc[kh * 3 + 2], acc);
        }
        float inv = g1[c] * rsqrtf(v1[c] + 1e-5f);
        float bb  = b1[c] - m1[c] * inv;
        float* op = h2p + ((size_t)(n * 64 + c) * PR + y + 1) * PC + xx + 1;
        op[0] = fmaxf(-acc.x * inv + bb, 0.f);
        op[1] = fmaxf(-acc.y * inv + bb, 0.f);
        op[2] = fmaxf(-acc.z * inv + bb, 0.f);
        op[3] = fmaxf(-acc.w * inv + bb, 0.f);
    } else if (t < 190464) {
        int i = t - 100352;
        int plane = i / 176, r = i % 176;
        int row, col;
        if (r < 64) { row = (r >> 5) * 29; col = r & 31; }
        else { int j = r - 64; row = 1 + (j >> 2); int k = j & 3; col = k ? 28 + k : 0; }
        h2p[(size_t)plane * (PR * PC) + row * PC + col] = 0.f;
    } else if (t < 227328) {
        int i = t - 190464;
        int r = i >> 6, c2 = i & 63;
        w2t[i] = w2[(size_t)c2 * 576 + r];
    } else if (t < 243712) {
        int i = t - 227328;
        int ci = i >> 8, c2 = i & 255;
        w3t[i] = w3[(size_t)c2 * 64 + ci];
    }
}

// ---------------- K3: 3x3 adder partials (8-ci slice) -> h3part. R22 proven. ----------------
// grid (7 Yq, 8 ciQ, 8 n) = 448 blocks, block 512 = 8 waves (wave = co-oct).
__global__ __launch_bounds__(512) void k3_part(const float* __restrict__ h2p,
                                               const float* __restrict__ w2t,
                                               float* __restrict__ h3part) {
    __shared__ __align__(16) float h2t[1728];    // [8 ci][6 rows][36]
    __shared__ __align__(16) float wt[4896];     // [72 r = ci*9+tap][68]
    const int tid  = threadIdx.x;
    const int lane = tid & 63;
    const int oct  = __builtin_amdgcn_readfirstlane(tid >> 6);   // 0..7
    const int col  = lane & 31;
    const int cih  = lane >> 5;          // 0..1
    const int Y0   = blockIdx.x * 4;     // output rows Y0..Y0+3
    const int ciQ  = blockIdx.y;         // 8 ci per block
    const int n    = blockIdx.z;

    for (int i = tid; i < 384; i += 512) {       // h2t: 8 ci x 6 rows x 8 f4
        int ci = i / 48, rem = i % 48;
        int r = rem >> 3, c4 = rem & 7;
        *(float4*)(h2t + ci * 216 + r * 36 + c4 * 4) =
            *(const float4*)(h2p + ((size_t)(n * 64 + ciQ * 8 + ci) * PR + Y0 + r) * PC + c4 * 4);
    }
    for (int i = tid; i < 1152; i += 512) {      // wt: 72 rows x 16 f4
        int row = i >> 4, c4 = i & 15;
        *(float4*)(wt + row * 68 + c4 * 4) =
            *(const float4*)(w2t + ((size_t)ciQ * 72 + row) * 64 + c4 * 4);
    }
    __syncthreads();

    float acc[4][8];
    #pragma unroll
    for (int r = 0; r < 4; ++r)
        #pragma unroll
        for (int j = 0; j < 8; ++j) acc[r][j] = 0.f;

    #pragma unroll
    for (int i = 0; i < 4; ++i) {
        const int ci_l = cih * 4 + i;            // 0..7
        float win[6][3];
        #pragma unroll
        for (int r = 0; r < 6; ++r)
            #pragma unroll
            for (int kw = 0; kw < 3; ++kw)
                win[r][kw] = h2t[ci_l * 216 + r * 36 + col + kw];
        const float* wrow = wt + ci_l * 612 + oct * 8;
        #pragma unroll
        for (int kh = 0; kh < 3; ++kh) {
            #pragma unroll
            for (int kw = 0; kw < 3; ++kw) {
                float4 wa = *(const float4*)(wrow + (kh * 3 + kw) * 68);
                float4 wb = *(const float4*)(wrow + (kh * 3 + kw) * 68 + 4);
                #pragma unroll
                for (int r = 0; r < 4; ++r) {
                    const float xv = win[r + kh][kw];
                    acc[r][0] += fabsf(xv - wa.x); acc[r][1] += fabsf(xv - wa.y);
                    acc[r][2] += fabsf(xv - wa.z); acc[r][3] += fabsf(xv - wa.w);
                    acc[r][4] += fabsf(xv - wb.x); acc[r][5] += fabsf(xv - wb.y);
                    acc[r][6] += fabsf(xv - wb.z); acc[r][7] += fabsf(xv - wb.w);
                }
            }
        }
    }
    #pragma unroll
    for (int r = 0; r < 4; ++r)
        #pragma unroll
        for (int j = 0; j < 8; ++j)
            acc[r][j] += __shfl_xor(acc[r][j], 32, 64);

    if (cih == 0 && col < 28) {
        #pragma unroll
        for (int r = 0; r < 4; ++r)
            #pragma unroll
            for (int j = 0; j < 8; ++j)
                h3part[(((size_t)ciQ * 8 + n) * 64 + oct * 8 + j) * 784 + (Y0 + r) * 28 + col] = acc[r][j];
    }
}

// ---------------- K6: sum 8 partials + BN2 + ReLU + 1x1 adder (w3s LDS-staged) + BN3 + res + ReLU ----------------
// SINGLE CHANGE vs R24: co-halved blocks. grid (28 Y, 2 coH, 8 n) = 448 blocks, block 256.
// w3s LDS staging RESTORED (R25 proved global-w3 is -13us); now half-size [64][132] = 33KB.
__global__ __launch_bounds__(256) void k6_fused(const float* __restrict__ h3part,
                                                const float* __restrict__ w3t,
                                                const float* __restrict__ x,
                                                const float* __restrict__ g2,
                                                const float* __restrict__ b2,
                                                const float* __restrict__ m2,
                                                const float* __restrict__ v2,
                                                const float* __restrict__ g3,
                                                const float* __restrict__ b3,
                                                const float* __restrict__ m3,
                                                const float* __restrict__ v3,
                                                float* __restrict__ out) {
    __shared__ __align__(16) float h3t[2048];    // [64 ci][32]
    __shared__ __align__(16) float w3s[8448];    // [64 ci][132] (128 co + 4 pad)
    const int tid = threadIdx.x;
    const int Y   = blockIdx.x;
    const int coH = blockIdx.y;          // co half
    const int n   = blockIdx.z;

    // stage h3t: sum 8 ci-slice partials + BN2 + ReLU
    for (int iq = tid; iq < 448; iq += 256) {
        const int ci = iq / 7, c4 = iq % 7;
        size_t base = ((size_t)n * 64 + ci) * 784 + Y * 28 + c4 * 4;
        const size_t qstride = (size_t)8 * 64 * 784;
        float4 s = *(const float4*)(h3part + base);
        #pragma unroll
        for (int qq = 1; qq < 8; ++qq) {
            float4 t = *(const float4*)(h3part + qq * qstride + base);
            s.x += t.x; s.y += t.y; s.z += t.z; s.w += t.w;
        }
        float inv = g2[ci] * rsqrtf(v2[ci] + 1e-5f);
        float bb  = b2[ci] - m2[ci] * inv;
        float4 o;
        o.x = fmaxf(-s.x * inv + bb, 0.f);
        o.y = fmaxf(-s.y * inv + bb, 0.f);
        o.z = fmaxf(-s.z * inv + bb, 0.f);
        o.w = fmaxf(-s.w * inv + bb, 0.f);
        *(float4*)(h3t + ci * 32 + c4 * 4) = o;
    }
    // stage w3s: this half's 128 cos (f4, coalesced, conflict-free)
    for (int iq = tid; iq < 2048; iq += 256) {
        int ci = iq >> 5, cq = iq & 31;
        *(float4*)(w3s + ci * 132 + cq * 4) =
            *(const float4*)(w3t + (size_t)ci * 256 + coH * 128 + cq * 4);
    }
    __syncthreads();

    {
        const int bl = tid & 31;          // co-quad within half: co = coH*128 + bl*4
        const int pg = tid >> 5;          // px-quad group 0..7 (7 active)
        float4 c0 = {0,0,0,0}, c1 = c0, c2 = c0, c3 = c0;
        const float* hb = h3t + pg * 4;
        const float* wb = w3s + bl * 4;
        #pragma unroll 8
        for (int ci = 0; ci < 64; ++ci) {
            float4 h = *(const float4*)(hb + ci * 32);       // broadcast
            float4 w = *(const float4*)(wb + ci * 132);
            c0.x += fabsf(h.x - w.x); c0.y += fabsf(h.y - w.x); c0.z += fabsf(h.z - w.x); c0.w += fabsf(h.w - w.x);
            c1.x += fabsf(h.x - w.y); c1.y += fabsf(h.y - w.y); c1.z += fabsf(h.z - w.y); c1.w += fabsf(h.w - w.y);
            c2.x += fabsf(h.x - w.z); c2.y += fabsf(h.y - w.z); c2.z += fabsf(h.z - w.z); c2.w += fabsf(h.w - w.z);
            c3.x += fabsf(h.x - w.w); c3.y += fabsf(h.y - w.w); c3.z += fabsf(h.z - w.w); c3.w += fabsf(h.w - w.w);
        }
        if (pg < 7) {
            float4 accs[4] = {c0, c1, c2, c3};
            #pragma unroll
            for (int j = 0; j < 4; ++j) {
                const int co = coH * 128 + bl * 4 + j;
                float inv = g3[co] * rsqrtf(v3[co] + 1e-5f);
                float bb  = b3[co] - m3[co] * inv;
                size_t obase = ((size_t)n * 256 + co) * 784 + Y * 28 + pg * 4;
                float4 r = *(const float4*)(x + obase);
                float4 o;
                o.x = fmaxf(-accs[j].x * inv + bb + r.x, 0.f);
                o.y = fmaxf(-accs[j].y * inv + bb + r.y, 0.f);
                o.z = fmaxf(-accs[j].z * inv + bb + r.z, 0.f);
                o.w = fmaxf(-accs[j].w * inv + bb + r.w, 0.f);
                *(float4*)(out + obase) = o;
            }
        }
    }
}

extern "C" void kernel_launch(void* const* d_in, const int* in_sizes, int n_in,
                              void* d_out, int out_size, void* d_ws, size_t ws_size,
                              hipStream_t stream) {
    const float* x  = (const float*)d_in[0];
    const float* w1 = (const float*)d_in[1];
    const float* wp = (const float*)d_in[2];
    const float* w2 = (const float*)d_in[3];
    const float* w3 = (const float*)d_in[4];
    const float* g1 = (const float*)d_in[5];
    const float* b1 = (const float*)d_in[6];
    const float* m1 = (const float*)d_in[7];
    const float* v1 = (const float*)d_in[8];
    const float* g2 = (const float*)d_in[9];
    const float* b2 = (const float*)d_in[10];
    const float* m2 = (const float*)d_in[11];
    const float* v2 = (const float*)d_in[12];
    const float* g3 = (const float*)d_in[13];
    const float* b3 = (const float*)d_in[14];
    const float* m3 = (const float*)d_in[15];
    const float* v3 = (const float*)d_in[16];
    float* out = (float*)d_out;

    float* wsf     = (float*)d_ws;
    float* h1p     = wsf;                 // 491520
    float* h2p     = wsf + 491520;        // 491520
    float* w2t     = wsf + 983040;        // 36864 [576 r][64 co]
    float* w3t     = wsf + 1019904;       // 16384 [64 ci][256 co]
    float* h3part  = wsf + 1036288;       // 8*8*64*784 = 3211264

    k1_adder1x1<<<dim3(224, 4), 448, 0, stream>>>(x, w1, h1p);
    k2_peg_bn_relu<<<dim3(952), 256, 0, stream>>>(h1p, wp, w2, w3,
                                                  g1, b1, m1, v1, h2p, w2t, w3t);
    k3_part<<<dim3(7, 8, 8), 512, 0, stream>>>(h2p, w2t, h3part);
    k6_fused<<<dim3(28, 2, 8), 256, 0, stream>>>(h3part, w3t, x,
                                                 g2, b2, m2, v2, g3, b3, m3, v3, out);
}

// Round 27
// 57.467 us; speedup vs baseline: 1.2547x; 1.0450x over previous
//
#include <hip/hip_runtime.h>
#include <math.h>

#define PR 30            // padded rows
#define PC 32            // padded col stride

__device__ __forceinline__ void tap3(const float4 a, const float2 b,
                                     const float w0, const float w1, const float w2,
                                     float4& acc) {
    acc.x += fabsf(a.x - w0) + fabsf(a.y - w1) + fabsf(a.z - w2);
    acc.y += fabsf(a.y - w0) + fabsf(a.z - w1) + fabsf(a.w - w2);
    acc.z += fabsf(a.z - w0) + fabsf(a.w - w1) + fabsf(b.x - w2);
    acc.w += fabsf(a.w - w0) + fabsf(b.x - w1) + fabsf(b.y - w2);
}

// ---------------- K1: 1x1 adder 256->64 -> PADDED h1p (halos folded) + w2t/w3t transposes ----------------
// grid (224, 4), block 448. Body = R22 proven; transposes added in spare thread-IDs.
__global__ __launch_bounds__(448) void k1_adder1x1(const float* __restrict__ x,
                                                   const float* __restrict__ w1,
                                                   const float* __restrict__ w2,
                                                   const float* __restrict__ w3,
                                                   float* __restrict__ h1p,
                                                   float* __restrict__ w2t,
                                                   float* __restrict__ w3t) {
    __shared__ __align__(16) float smem[7168];   // ws [256][20] (5120) union pl (7168)
    float*  ws  = smem;
    float4* pl4 = (float4*)smem;
    const int tid    = threadIdx.x;
    const int cog    = tid & 3;
    const int pxg    = (tid >> 2) % 7;
    const int cic    = tid / 28;                 // 0..15
    const int n      = blockIdx.x / 28;
    const int y      = blockIdx.x % 28;
    const int px0    = y * 28 + pxg * 4;
    const int cobase = blockIdx.y * 16;

    // weight transposes for k3/k6 (consumed in later launches; stream-ordered)
    {
        const int bid3 = blockIdx.x + 224 * blockIdx.y;
        const int tg = bid3 * 448 + tid;
        if (tg < 36864) {
            int r = tg >> 6, c2 = tg & 63;
            w2t[tg] = w2[(size_t)c2 * 576 + r];          // w2t[r*64+co]
        } else if (tg < 53248) {
            int i = tg - 36864;
            int ci = i >> 8, c2 = i & 255;
            w3t[i] = w3[(size_t)c2 * 64 + ci];           // w3t[ci*256+co]
        }
    }

    for (int idx = tid; idx < 4096; idx += 448) {
        int co = idx >> 8, ci = idx & 255;
        ws[ci * 20 + co] = w1[(size_t)(cobase + co) * 256 + ci];
    }
    __syncthreads();

    float4 acc0 = {0,0,0,0}, acc1 = acc0, acc2 = acc0, acc3 = acc0;
    const float* xp = x + ((size_t)n * 256 + cic * 16) * 784 + px0;
    const float* wp = ws + (cic * 16) * 20 + cog * 4;
    #pragma unroll 8
    for (int i = 0; i < 16; ++i) {
        float4 u = *(const float4*)(xp + (size_t)i * 784);
        float4 w = *(const float4*)(wp + i * 20);
        acc0.x += fabsf(u.x - w.x); acc0.y += fabsf(u.y - w.x); acc0.z += fabsf(u.z - w.x); acc0.w += fabsf(u.w - w.x);
        acc1.x += fabsf(u.x - w.y); acc1.y += fabsf(u.y - w.y); acc1.z += fabsf(u.z - w.y); acc1.w += fabsf(u.w - w.y);
        acc2.x += fabsf(u.x - w.z); acc2.y += fabsf(u.y - w.z); acc2.z += fabsf(u.z - w.z); acc2.w += fabsf(u.w - w.z);
        acc3.x += fabsf(u.x - w.w); acc3.y += fabsf(u.y - w.w); acc3.z += fabsf(u.z - w.w); acc3.w += fabsf(u.w - w.w);
    }
    __syncthreads();
    const int pbase = pxg * 16 + cog * 4;
    pl4[cic * 112 + pbase + 0] = acc0;
    pl4[cic * 112 + pbase + 1] = acc1;
    pl4[cic * 112 + pbase + 2] = acc2;
    pl4[cic * 112 + pbase + 3] = acc3;
    __syncthreads();

    if (tid < 112) {
        const int rpxg = tid >> 4;
        const int rcog = (tid >> 2) & 3;
        const int j    = tid & 3;
        const int rb   = rpxg * 16 + rcog * 4 + j;
        float4 s = pl4[rb];
        #pragma unroll
        for (int c = 1; c < 16; ++c) {
            float4 t = pl4[c * 112 + rb];
            s.x += t.x; s.y += t.y; s.z += t.z; s.w += t.w;
        }
        const int co = cobase + rcog * 4 + j;
        float* op = h1p + ((size_t)(n * 64 + co) * PR + y + 1) * PC + rpxg * 4 + 1;
        op[0] = -s.x; op[1] = -s.y; op[2] = -s.z; op[3] = -s.w;
        if (rpxg == 0) op[-1] = 0.f;
        if (rpxg == 6) { op[4] = 0.f; op[5] = 0.f; op[6] = 0.f; }
    }
    if (y == 0 || y == 27) {
        const int prow = (y == 0) ? 0 : 29;
        for (int idx = tid; idx < 512; idx += 448) {
            int coi = idx >> 5, col = idx & 31;
            h1p[((size_t)(n * 64 + cobase + coi) * PR + prow) * PC + col] = 0.f;
        }
    }
}

// ---------------- K3: inline PEG+BN1+ReLU (from h1p) then 3x3 adder partials -> h3part ----------------
// grid (7 Yq, 8 ciQ, 8 n) = 448 blocks, block 512 = 8 waves (wave = co-oct).
// Staging now computes h2 rows in LDS directly from h1p (k2 deleted; 1.5x PEG recompute, trivial).
// Main loop byte-identical to the 59.0us R24 k3_part.
__global__ __launch_bounds__(512) void k3_part(const float* __restrict__ h1p,
                                               const float* __restrict__ wpeg,
                                               const float* __restrict__ w2t,
                                               const float* __restrict__ g1,
                                               const float* __restrict__ b1,
                                               const float* __restrict__ m1,
                                               const float* __restrict__ v1,
                                               float* __restrict__ h3part) {
    __shared__ __align__(16) float h1t[2304];    // [8 ci][8 rows][36]
    __shared__ __align__(16) float h2t[1728];    // [8 ci][6 rows][36]
    __shared__ __align__(16) float wt[4896];     // [72 r = ci*9+tap][68]
    __shared__ float wpg[72];                    // [8 ci][9]
    const int tid  = threadIdx.x;
    const int lane = tid & 63;
    const int oct  = __builtin_amdgcn_readfirstlane(tid >> 6);   // 0..7
    const int col  = lane & 31;
    const int cih  = lane >> 5;          // 0..1
    const int Y0   = blockIdx.x * 4;     // output rows Y0..Y0+3
    const int ciQ  = blockIdx.y;         // 8 ci per block
    const int n    = blockIdx.z;

    // stage h1t: 8 ci x padded rows (Y0-1 .. Y0+6, clamped) x 32 cols (f4 coalesced)
    {
        int ci = tid >> 6, lr = (tid >> 3) & 7, c4 = tid & 7;
        int gr = Y0 - 1 + lr;
        gr = gr < 0 ? 0 : (gr > 29 ? 29 : gr);   // clamped rows only feed unused halo cells
        *(float4*)(h1t + ci * 288 + lr * 36 + c4 * 4) =
            *(const float4*)(h1p + ((size_t)(n * 64 + ciQ * 8 + ci) * PR + gr) * PC + c4 * 4);
    }
    for (int i = tid; i < 1152; i += 512) {      // wt: 72 rows x 16 f4
        int row = i >> 4, c4 = i & 15;
        *(float4*)(wt + row * 68 + c4 * 4) =
            *(const float4*)(w2t + ((size_t)ciQ * 72 + row) * 64 + c4 * 4);
    }
    if (tid < 72) wpg[tid] = wpeg[(ciQ * 8 + tid / 9) * 9 + tid % 9];
    __syncthreads();

    // compute h2t = PEG + BN1 + ReLU (padded rows Y0..Y0+5; halo cells = 0)
    for (int i = tid; i < 1536; i += 512) {
        int ci = i / 192, rem = i % 192;
        int r = rem >> 5, c = rem & 31;          // padded row Y0+r, padded col c
        int pr = Y0 + r;
        float val = 0.f;
        if (c >= 1 && c <= 28 && pr >= 1 && pr <= 28) {
            const float* hb = h1t + ci * 288 + r * 36 + (c - 1);
            const float* wc = wpg + ci * 9;
            float a = 0.f;
            #pragma unroll
            for (int kh = 0; kh < 3; ++kh)
                #pragma unroll
                for (int kw = 0; kw < 3; ++kw)
                    a += fabsf(hb[kh * 36 + kw] - wc[kh * 3 + kw]);
            const int gci = ciQ * 8 + ci;
            float inv = g1[gci] * rsqrtf(v1[gci] + 1e-5f);
            float bb  = b1[gci] - m1[gci] * inv;
            val = fmaxf(-a * inv + bb, 0.f);
        }
        h2t[ci * 216 + r * 36 + c] = val;
    }
    __syncthreads();

    float acc[4][8];
    #pragma unroll
    for (int r = 0; r < 4; ++r)
        #pragma unroll
        for (int j = 0; j < 8; ++j) acc[r][j] = 0.f;

    #pragma unroll
    for (int i = 0; i < 4; ++i) {
        const int ci_l = cih * 4 + i;            // 0..7
        float win[6][3];
        #pragma unroll
        for (int r = 0; r < 6; ++r)
            #pragma unroll
            for (int kw = 0; kw < 3; ++kw)
                win[r][kw] = h2t[ci_l * 216 + r * 36 + col + kw];
        const float* wrow = wt + ci_l * 612 + oct * 8;
        #pragma unroll
        for (int kh = 0; kh < 3; ++kh) {
            #pragma unroll
            for (int kw = 0; kw < 3; ++kw) {
                float4 wa = *(const float4*)(wrow + (kh * 3 + kw) * 68);
                float4 wb = *(const float4*)(wrow + (kh * 3 + kw) * 68 + 4);
                #pragma unroll
                for (int r = 0; r < 4; ++r) {
                    const float xv = win[r + kh][kw];
                    acc[r][0] += fabsf(xv - wa.x); acc[r][1] += fabsf(xv - wa.y);
                    acc[r][2] += fabsf(xv - wa.z); acc[r][3] += fabsf(xv - wa.w);
                    acc[r][4] += fabsf(xv - wb.x); acc[r][5] += fabsf(xv - wb.y);
                    acc[r][6] += fabsf(xv - wb.z); acc[r][7] += fabsf(xv - wb.w);
                }
            }
        }
    }
    #pragma unroll
    for (int r = 0; r < 4; ++r)
        #pragma unroll
        for (int j = 0; j < 8; ++j)
            acc[r][j] += __shfl_xor(acc[r][j], 32, 64);

    if (cih == 0 && col < 28) {
        #pragma unroll
        for (int r = 0; r < 4; ++r)
            #pragma unroll
            for (int j = 0; j < 8; ++j)
                h3part[(((size_t)ciQ * 8 + n) * 64 + oct * 8 + j) * 784 + (Y0 + r) * 28 + col] = acc[r][j];
    }
}

// ---------------- K6: sum 8 partials + BN2 + ReLU + 1x1 adder 64->256 + BN3 + res + ReLU. R24 proven. ----------------
// grid (28 Y, 8 n) = 224 blocks, block 512.
__global__ __launch_bounds__(512) void k6_fused(const float* __restrict__ h3part,
                                                const float* __restrict__ w3t,
                                                const float* __restrict__ x,
                                                const float* __restrict__ g2,
                                                const float* __restrict__ b2,
                                                const float* __restrict__ m2,
                                                const float* __restrict__ v2,
                                                const float* __restrict__ g3,
                                                const float* __restrict__ b3,
                                                const float* __restrict__ m3,
                                                const float* __restrict__ v3,
                                                float* __restrict__ out) {
    __shared__ __align__(16) float h3t[2048];    // [64 ci][32]
    __shared__ __align__(16) float w3s[16896];   // [64 ci][264]
    const int tid = threadIdx.x;
    const int Y   = blockIdx.x;
    const int n   = blockIdx.y;

    if (tid < 448) {
        const int co = tid / 7, c4 = tid % 7;
        size_t base = ((size_t)n * 64 + co) * 784 + Y * 28 + c4 * 4;
        const size_t qstride = (size_t)8 * 64 * 784;
        float4 s = *(const float4*)(h3part + base);
        #pragma unroll
        for (int qq = 1; qq < 8; ++qq) {
            float4 t = *(const float4*)(h3part + qq * qstride + base);
            s.x += t.x; s.y += t.y; s.z += t.z; s.w += t.w;
        }
        float inv = g2[co] * rsqrtf(v2[co] + 1e-5f);
        float bb  = b2[co] - m2[co] * inv;
        float4 o;
        o.x = fmaxf(-s.x * inv + bb, 0.f);
        o.y = fmaxf(-s.y * inv + bb, 0.f);
        o.z = fmaxf(-s.z * inv + bb, 0.f);
        o.w = fmaxf(-s.w * inv + bb, 0.f);
        *(float4*)(h3t + co * 32 + c4 * 4) = o;
    }
    for (int iq = tid; iq < 4096; iq += 512) {
        int ci = iq >> 6, cq = iq & 63;
        *(float4*)(w3s + ci * 264 + cq * 4) =
            *(const float4*)(w3t + (size_t)ci * 256 + cq * 4);
    }
    __syncthreads();

    {
        const int bl = tid & 63;          // co-quad: co = bl*4..+3
        const int pg = tid >> 6;          // px-quad group; px = pg*4..+3
        float4 c0 = {0,0,0,0}, c1 = c0, c2 = c0, c3 = c0;
        const float* hb = h3t + pg * 4;
        const float* wb = w3s + bl * 4;
        #pragma unroll 8
        for (int ci = 0; ci < 64; ++ci) {
            float4 h = *(const float4*)(hb + ci * 32);       // broadcast
            float4 w = *(const float4*)(wb + ci * 264);
            c0.x += fabsf(h.x - w.x); c0.y += fabsf(h.y - w.x); c0.z += fabsf(h.z - w.x); c0.w += fabsf(h.w - w.x);
            c1.x += fabsf(h.x - w.y); c1.y += fabsf(h.y - w.y); c1.z += fabsf(h.z - w.y); c1.w += fabsf(h.w - w.y);
            c2.x += fabsf(h.x - w.z); c2.y += fabsf(h.y - w.z); c2.z += fabsf(h.z - w.z); c2.w += fabsf(h.w - w.z);
            c3.x += fabsf(h.x - w.w); c3.y += fabsf(h.y - w.w); c3.z += fabsf(h.z - w.w); c3.w += fabsf(h.w - w.w);
        }
        if (pg < 7) {
            float4 accs[4] = {c0, c1, c2, c3};
            #pragma unroll
            for (int j = 0; j < 4; ++j) {
                const int co = bl * 4 + j;
                float inv = g3[co] * rsqrtf(v3[co] + 1e-5f);
                float bb  = b3[co] - m3[co] * inv;
                size_t obase = ((size_t)n * 256 + co) * 784 + Y * 28 + pg * 4;
                float4 r = *(const float4*)(x + obase);
                float4 o;
                o.x = fmaxf(-accs[j].x * inv + bb + r.x, 0.f);
                o.y = fmaxf(-accs[j].y * inv + bb + r.y, 0.f);
                o.z = fmaxf(-accs[j].z * inv + bb + r.z, 0.f);
                o.w = fmaxf(-accs[j].w * inv + bb + r.w, 0.f);
                *(float4*)(out + obase) = o;
            }
        }
    }
}

extern "C" void kernel_launch(void* const* d_in, const int* in_sizes, int n_in,
                              void* d_out, int out_size, void* d_ws, size_t ws_size,
                              hipStream_t stream) {
    const float* x  = (const float*)d_in[0];
    const float* w1 = (const float*)d_in[1];
    const float* wp = (const float*)d_in[2];
    const float* w2 = (const float*)d_in[3];
    const float* w3 = (const float*)d_in[4];
    const float* g1 = (const float*)d_in[5];
    const float* b1 = (const float*)d_in[6];
    const float* m1 = (const float*)d_in[7];
    const float* v1 = (const float*)d_in[8];
    const float* g2 = (const float*)d_in[9];
    const float* b2 = (const float*)d_in[10];
    const float* m2 = (const float*)d_in[11];
    const float* v2 = (const float*)d_in[12];
    const float* g3 = (const float*)d_in[13];
    const float* b3 = (const float*)d_in[14];
    const float* m3 = (const float*)d_in[15];
    const float* v3 = (const float*)d_in[16];
    float* out = (float*)d_out;

    float* wsf     = (float*)d_ws;
    float* h1p     = wsf;                 // 491520
    float* w2t     = wsf + 491520;        // 36864 [576 r][64 co]
    float* w3t     = wsf + 528384;        // 16384 [64 ci][256 co]
    float* h3part  = wsf + 544768;        // 8*8*64*784 = 3211264

    k1_adder1x1<<<dim3(224, 4), 448, 0, stream>>>(x, w1, w2, w3, h1p, w2t, w3t);
    k3_part<<<dim3(7, 8, 8), 512, 0, stream>>>(h1p, wp, w2t, g1, b1, m1, v1, h3part);
    k6_fused<<<dim3(28, 8), 512, 0, stream>>>(h3part, w3t, x,
                                              g2, b2, m2, v2, g3, b3, m3, v3, out);
}